// Round 17
// baseline (73.026 us; speedup 1.0000x reference)
//
#include <hip/hip_runtime.h>

#define N_B 2
#define L_L 2048
#define E_E 1024
#define H_H 16
#define D_H 64
#define LDSP 72  // padded LDS row stride (ushorts) for qkv kernel

typedef __bf16 bf16x8 __attribute__((ext_vector_type(8)));
typedef float f32x4 __attribute__((ext_vector_type(4)));
typedef short s16x8 __attribute__((ext_vector_type(8)));
typedef unsigned short u16x4 __attribute__((ext_vector_type(4)));

__device__ __forceinline__ f32x4 mfma16(bf16x8 a, bf16x8 b, f32x4 c) {
  return __builtin_amdgcn_mfma_f32_16x16x32_bf16(a, b, c, 0, 0, 0);
}

__device__ __forceinline__ unsigned short f2bf(float x) {
  unsigned int u = __float_as_uint(x);
  u = (u + 0x7fffu + ((u >> 16) & 1u)) >> 16;
  return (unsigned short)u;
}

__device__ __forceinline__ unsigned int cvtpk(float lo, float hi) {
  unsigned int r;
  asm("v_cvt_pk_bf16_f32 %0, %1, %2" : "=v"(r) : "v"(lo), "v"(hi));
  return r;
}

__device__ __forceinline__ void swap32(unsigned int& a, unsigned int& b) {
  asm("v_permlane32_swap_b32 %0, %1" : "+v"(a), "+v"(b));
}
__device__ __forceinline__ void swap16(unsigned int& a, unsigned int& b) {
  asm("v_permlane16_swap_b32 %0, %1" : "+v"(a), "+v"(b));
}

__device__ __forceinline__ float exp2a(float x) {  // 2^x, single v_exp_f32
  float r;
  asm("v_exp_f32 %0, %1" : "=v"(r) : "v"(x));
  return r;
}

// async global->LDS 16B DMA (dest linear per wave)
__device__ __forceinline__ void gload16(const void* g, void* l) {
  __builtin_amdgcn_global_load_lds(
      (__attribute__((address_space(1))) void*)g,
      (__attribute__((address_space(3))) void*)l, 16, 0, 0);
}

// Build PV A-fragment from swapped-QK^T C-layout values (in-register, T12).
__device__ __forceinline__ bf16x8 pack_frag(const f32x4& plo, const f32x4& phi) {
  unsigned int x0 = cvtpk(plo[0], plo[1]), x1 = cvtpk(plo[2], plo[3]);
  unsigned int x2 = cvtpk(phi[0], phi[1]), x3 = cvtpk(phi[2], phi[3]);
  swap32(x0, x2); swap16(x0, x2);
  swap32(x1, x3); swap16(x1, x3);
  union { unsigned int u[4]; bf16x8 v; } f;
  f.u[0] = x0; f.u[1] = x1; f.u[2] = x2; f.u[3] = x3;
  return f.v;
}

// K1: QKV projection as MFMA GEMM (round-8 structure).
__global__ __launch_bounds__(256) void qkv_gemm_kernel(
    const float* __restrict__ EPq, const float* __restrict__ EPk, const float* __restrict__ EPv,
    const float* __restrict__ Wq, const float* __restrict__ Wk, const float* __restrict__ Wv,
    const float* __restrict__ bq, const float* __restrict__ bk, const float* __restrict__ bv,
    const float* __restrict__ Wo, unsigned short* __restrict__ Wob,
    unsigned short* __restrict__ Qb, unsigned short* __restrict__ Kb,
    unsigned short* __restrict__ Vtb) {
  __shared__ __attribute__((aligned(16))) unsigned short Xs[64][LDSP];
  __shared__ __attribute__((aligned(16))) unsigned short Ws[64][LDSP];
  const int tid = threadIdx.x;
  const int wid = tid >> 6;
  const int lane = tid & 63;
  const int lr = lane & 15;
  const int lg = lane >> 4;
  const int nh = blockIdx.x >> 5;
  const int l0 = (blockIdx.x & 31) * 64;
  const int n = nh >> 4;
  const int h = nh & 15;
  const float SCQ = 0.03125f * 1.44269504089f;

  {
    const int i = blockIdx.x * 256 + tid;
    const float4 f = ((const float4*)Wo)[i];
    u16x4 v = { f2bf(f.x), f2bf(f.y), f2bf(f.z), f2bf(f.w) };
    *(u16x4*)&Wob[(size_t)i * 4] = v;
  }

  #pragma unroll
  for (int mat = 0; mat < 3; ++mat) {
    const float* X = (mat == 0) ? EPq : (mat == 1) ? EPk : EPv;
    const float* W = (mat == 0) ? Wq : (mat == 1) ? Wk : Wv;
    const float* bias = (mat == 0) ? bq : (mat == 1) ? bk : bv;
    const float osc = (mat == 0) ? SCQ : 1.0f;

    const float* xb = X + ((size_t)(n * L_L + l0)) * E_E + h * D_H;
    #pragma unroll
    for (int it = 0; it < 4; ++it) {
      const int idx = it * 256 + tid;
      const int row = idx >> 4, c = idx & 15;
      const float4 f = *(const float4*)(xb + (size_t)row * E_E + c * 4);
      u16x4 v = { f2bf(f.x), f2bf(f.y), f2bf(f.z), f2bf(f.w) };
      *(u16x4*)&Xs[row][c * 4] = v;
    }
    #pragma unroll
    for (int it = 0; it < 4; ++it) {
      const int idx = it * 256 + tid;
      const int row = idx >> 4, c = idx & 15;
      const float4 f = *(const float4*)(W + idx * 4);
      u16x4 v = { f2bf(f.x), f2bf(f.y), f2bf(f.z), f2bf(f.w) };
      *(u16x4*)&Ws[row][c * 4] = v;
    }
    __syncthreads();

    const bf16x8 a0 = *(const bf16x8*)&Xs[wid * 16 + lr][lg * 8];
    const bf16x8 a1 = *(const bf16x8*)&Xs[wid * 16 + lr][32 + lg * 8];
    f32x4 acc[4];
    #pragma unroll
    for (int t = 0; t < 4; ++t) {
      const float bb = bias[t * 16 + lr];
      acc[t] = f32x4{bb, bb, bb, bb};
      const bf16x8 b0 = *(const bf16x8*)&Ws[t * 16 + lr][lg * 8];
      const bf16x8 b1 = *(const bf16x8*)&Ws[t * 16 + lr][32 + lg * 8];
      acc[t] = mfma16(a0, b0, acc[t]);
      acc[t] = mfma16(a1, b1, acc[t]);
    }
    __syncthreads();

    #pragma unroll
    for (int t = 0; t < 4; ++t)
      #pragma unroll
      for (int r = 0; r < 4; ++r)
        Xs[wid * 16 + lg * 4 + r][t * 16 + lr] = f2bf(acc[t][r] * osc);
    __syncthreads();

    if (mat < 2) {
      unsigned short* dst = ((mat == 0) ? Qb : Kb) + ((size_t)nh * L_L + l0) * D_H;
      #pragma unroll
      for (int it = 0; it < 2; ++it) {
        const int idx = it * 256 + tid;
        const int row = idx >> 3, c = idx & 7;
        *(s16x8*)(dst + (size_t)row * D_H + c * 8) = *(s16x8*)&Xs[row][c * 8];
      }
    } else {
      #pragma unroll
      for (int it = 0; it < 2; ++it) {
        const int idx = it * 256 + tid;
        const int d = idx & 63, c = idx >> 6;
        s16x8 v;
        #pragma unroll
        for (int j = 0; j < 8; ++j) v[j] = (short)Xs[c * 8 + j][d];
        *(s16x8*)(Vtb + ((size_t)nh * D_H + d) * L_L + l0 + c * 8) = v;
      }
    }
    __syncthreads();
  }
}

// K2: flash attention, r13 pipeline + T3/T4 counted vmcnt:
// 3-deep K and V LDS buffers (48 KB), raw s_barrier with s_waitcnt vmcnt(N)
// so the current body's DMA loads stay in flight across the barrier.
// Body t: QKT(t+1) reads KS[(t+1)%3]; STAGE_K(t+3)->KS[t%3];
//         STAGE_V(t+2)->VS[(t+2)%3]; SMPV(t) reads VS[t%3]; vmcnt(4); bar.
__global__ __launch_bounds__(256, 2) void attn_mfma_kernel(
    const unsigned short* __restrict__ Qb, const unsigned short* __restrict__ Kb,
    const unsigned short* __restrict__ Vtb, unsigned short* __restrict__ Ab) {
  __shared__ __attribute__((aligned(16))) unsigned short KS[3][64][64]; // 24 KB
  __shared__ __attribute__((aligned(16))) unsigned short VS[3][64][64]; // 24 KB

  const int tid = threadIdx.x;
  const int wid = tid >> 6;       // 0..3
  const int lane = tid & 63;
  const int lr = lane & 15;
  const int lg = lane >> 4;

  const int bid = ((blockIdx.x & 7) << 6) + (blockIdx.x >> 3);
  const int nh = bid >> 4;
  const int q0w = ((bid & 15) << 7) + wid * 32;   // 32 q-rows per wave

  const unsigned short* gQ = Qb + ((size_t)nh * L_L + q0w) * D_H;
  const unsigned short* gK = Kb + (size_t)nh * L_L * D_H;
  const unsigned short* gV = Vtb + (size_t)nh * D_H * L_L;

  bf16x8 bQ[2][2];
  #pragma unroll
  for (int qb = 0; qb < 2; ++qb)
    #pragma unroll
    for (int c2 = 0; c2 < 2; ++c2)
      bQ[qb][c2] = *(const bf16x8*)(gQ + (qb * 16 + lr) * D_H + c2 * 32 + lg * 8);

  const s16x8 ones16 = {0x3F80,0x3F80,0x3F80,0x3F80,0x3F80,0x3F80,0x3F80,0x3F80};
  const bf16x8 ones = *(const bf16x8*)&ones16;

  const int srow0 = tid >> 3, sch0 = tid & 7;
  const int srow1 = srow0 + 32;
  const int kc0 = (sch0 ^ (srow0 & 7)) * 8;
  const int kc1 = (sch0 ^ (srow1 & 7)) * 8;

  #define STAGE_K(kd, ktt)                                                     \
    do {                                                                       \
      gload16(gK + (size_t)((ktt) * 64 + srow0) * D_H + kc0,                   \
              (kd) + srow0 * 64 + sch0 * 8);                                   \
      gload16(gK + (size_t)((ktt) * 64 + srow1) * D_H + kc1,                   \
              (kd) + srow1 * 64 + sch0 * 8);                                   \
    } while (0)
  #define STAGE_V(vd, ktt)                                                     \
    do {                                                                       \
      gload16(gV + (size_t)srow0 * L_L + (ktt) * 64 + kc0,                     \
              (vd) + srow0 * 64 + sch0 * 8);                                   \
      gload16(gV + (size_t)srow1 * L_L + (ktt) * 64 + kc1,                     \
              (vd) + srow1 * 64 + sch0 * 8);                                   \
    } while (0)

  f32x4 acc0[4] = {f32x4{0,0,0,0},f32x4{0,0,0,0},f32x4{0,0,0,0},f32x4{0,0,0,0}};
  f32x4 acc1[4] = {f32x4{0,0,0,0},f32x4{0,0,0,0},f32x4{0,0,0,0},f32x4{0,0,0,0}};
  f32x4 lacc0 = {0,0,0,0}, lacc1 = {0,0,0,0};
  f32x4 svA0[4], svA1[4], svB0[4], svB1[4];

  #define QKT(SQ0, SQ1, Kc_)                                                   \
    do {                                                                       \
      const char* Kc = (const char*)(Kc_);                                     \
      __builtin_amdgcn_s_setprio(1);                                           \
      _Pragma("unroll")                                                        \
      for (int kb = 0; kb < 4; ++kb) {                                         \
        const int row = kb * 16 + lr;                                          \
        const bf16x8 a0 = *(const bf16x8*)(Kc + row * 128 + ((lg ^ (row & 7)) << 4)); \
        const bf16x8 a1 = *(const bf16x8*)(Kc + row * 128 + (((4 + lg) ^ (row & 7)) << 4)); \
        SQ0[kb] = mfma16(a1, bQ[0][1], mfma16(a0, bQ[0][0], f32x4{0,0,0,0}));  \
        SQ1[kb] = mfma16(a1, bQ[1][1], mfma16(a0, bQ[1][0], f32x4{0,0,0,0}));  \
      }                                                                        \
      __builtin_amdgcn_s_setprio(0);                                           \
    } while (0)

  #define SMPV(SQ0, SQ1, Vc_)                                                  \
    do {                                                                       \
      _Pragma("unroll")                                                        \
      for (int kb = 0; kb < 4; ++kb)                                           \
        _Pragma("unroll")                                                      \
        for (int r = 0; r < 4; ++r) {                                          \
          SQ0[kb][r] = exp2a(SQ0[kb][r]);                                      \
          SQ1[kb][r] = exp2a(SQ1[kb][r]);                                      \
        }                                                                      \
      bf16x8 aP0[2], aP1[2];                                                   \
      aP0[0] = pack_frag(SQ0[0], SQ0[1]); aP0[1] = pack_frag(SQ0[2], SQ0[3]);  \
      aP1[0] = pack_frag(SQ1[0], SQ1[1]); aP1[1] = pack_frag(SQ1[2], SQ1[3]);  \
      const char* Vc = (const char*)(Vc_);                                     \
      __builtin_amdgcn_s_setprio(1);                                           \
      lacc0 = mfma16(aP0[0], ones, lacc0); lacc0 = mfma16(aP0[1], ones, lacc0);\
      lacc1 = mfma16(aP1[0], ones, lacc1); lacc1 = mfma16(aP1[1], ones, lacc1);\
      _Pragma("unroll")                                                        \
      for (int t = 0; t < 4; ++t) {                                            \
        const int row = t * 16 + lr;                                           \
        const bf16x8 v0 = *(const bf16x8*)(Vc + row * 128 + ((lg ^ (row & 7)) << 4)); \
        const bf16x8 v1 = *(const bf16x8*)(Vc + row * 128 + (((4 + lg) ^ (row & 7)) << 4)); \
        acc0[t] = mfma16(aP0[0], v0, acc0[t]); acc0[t] = mfma16(aP0[1], v1, acc0[t]); \
        acc1[t] = mfma16(aP1[0], v0, acc1[t]); acc1[t] = mfma16(aP1[1], v1, acc1[t]); \
      }                                                                        \
      __builtin_amdgcn_s_setprio(0);                                           \
    } while (0)

  #define CBAR(N)                                                              \
    do {                                                                       \
      asm volatile("s_waitcnt vmcnt(" #N ")" ::: "memory");                    \
      __builtin_amdgcn_s_barrier();                                            \
      __builtin_amdgcn_sched_barrier(0);                                       \
    } while (0)

  // prologue: K(0..2), V(0..1) in flight (10 loads/thread).
  STAGE_K(&KS[0][0][0], 0);
  STAGE_K(&KS[1][0][0], 1);
  STAGE_K(&KS[2][0][0], 2);
  STAGE_V(&VS[0][0][0], 0);
  STAGE_V(&VS[1][0][0], 1);
  CBAR(8);                       // K(0) complete everywhere
  QKT(svA0, svA1, &KS[0][0][0]);
  CBAR(2);                       // K(1),K(2),V(0) complete; V(1) may fly

  int kr = 1, kw = 0, vw = 2, vr = 0;   // (t+1)%3, t%3, (t+2)%3, t%3 at t=0
  #pragma unroll 1
  for (int t2 = 0; t2 < 14; ++t2) {
    // even body t = 2*t2
    {
      const int t = 2 * t2;
      QKT(svB0, svB1, &KS[kr][0][0]);
      STAGE_K(&KS[kw][0][0], t + 3);
      STAGE_V(&VS[vw][0][0], t + 2);
      SMPV(svA0, svA1, &VS[vr][0][0]);
      CBAR(4);                   // only this body's 4 loads may fly
      kr = (kr == 2) ? 0 : kr + 1; kw = (kw == 2) ? 0 : kw + 1;
      vw = (vw == 2) ? 0 : vw + 1; vr = (vr == 2) ? 0 : vr + 1;
    }
    // odd body t = 2*t2+1
    {
      const int t = 2 * t2 + 1;
      QKT(svA0, svA1, &KS[kr][0][0]);
      STAGE_K(&KS[kw][0][0], t + 3);
      STAGE_V(&VS[vw][0][0], t + 2);
      SMPV(svB0, svB1, &VS[vr][0][0]);
      CBAR(4);
      kr = (kr == 2) ? 0 : kr + 1; kw = (kw == 2) ? 0 : kw + 1;
      vw = (vw == 2) ? 0 : vw + 1; vr = (vr == 2) ? 0 : vr + 1;
    }
  }
  // tail: t = 28 (even, full), 29, 30, 31
  QKT(svB0, svB1, &KS[2][0][0]);       // K(29)
  STAGE_K(&KS[1][0][0], 31);
  STAGE_V(&VS[0][0][0], 30);
  SMPV(svA0, svA1, &VS[1][0][0]);      // V(28)
  CBAR(4);
  QKT(svA0, svA1, &KS[0][0][0]);       // K(30)
  STAGE_V(&VS[1][0][0], 31);
  SMPV(svB0, svB1, &VS[2][0][0]);      // V(29)
  CBAR(2);
  QKT(svB0, svB1, &KS[1][0][0]);       // K(31)
  SMPV(svA0, svA1, &VS[0][0][0]);      // V(30)
  CBAR(0);
  SMPV(svB0, svB1, &VS[1][0][0]);      // V(31)
  #undef STAGE_K
  #undef STAGE_V
  #undef QKT
  #undef SMPV
  #undef CBAR

  const int n = nh >> 4, h = nh & 15;
  #pragma unroll
  for (int qb = 0; qb < 2; ++qb) {
    const f32x4& la = qb ? lacc1 : lacc0;
    f32x4* ac = qb ? acc1 : acc0;
    f32x4 inv;
    #pragma unroll
    for (int r = 0; r < 4; ++r) inv[r] = 1.0f / la[r];
    const int qbase = q0w + qb * 16 + 4 * lg;
    #pragma unroll
    for (int t = 0; t < 4; ++t)
      #pragma unroll
      for (int r = 0; r < 4; ++r)
        Ab[((size_t)(n * L_L + qbase + r)) * E_E + h * D_H + t * 16 + lr] =
            f2bf(ac[t][r] * inv[r]);
  }
}

// K3: out = A(bf16) @ Wo^T(bf16) + bo, fp32 out (round-8 structure).
__global__ __launch_bounds__(256, 2) void out_gemm_kernel(
    const unsigned short* __restrict__ Ab, const unsigned short* __restrict__ Wob,
    const float* __restrict__ bo, float* __restrict__ out) {
  __shared__ __attribute__((aligned(16))) unsigned short As[2][64][64];   // 16KB
  __shared__ __attribute__((aligned(16))) unsigned short Bs[2][128][64];  // 32KB
  const int tid = threadIdx.x;
  const int wid = tid >> 6;
  const int lane = tid & 63;
  const int lr = lane & 15;
  const int lg = lane >> 4;

  const int bid = ((blockIdx.x & 7) << 6) + (blockIdx.x >> 3);
  const int m0 = (bid >> 3) * 64;
  const int n0 = (bid & 7) * 128;
  const int wr = wid >> 1, wc = wid & 1;

  const int r0 = tid >> 3, sc = tid & 7;
  const int scol = (sc ^ (r0 & 7)) * 8;

  #define OSTAGE(buf, kt)                                                      \
    do {                                                                       \
      unsigned short* ad = &As[buf][0][0];                                     \
      unsigned short* bd = &Bs[buf][0][0];                                     \
      gload16(Ab + (size_t)(m0 + r0) * E_E + (kt) * 64 + scol,                 \
              ad + r0 * 64 + sc * 8);                                          \
      gload16(Ab + (size_t)(m0 + r0 + 32) * E_E + (kt) * 64 + scol,            \
              ad + (r0 + 32) * 64 + sc * 8);                                   \
      gload16(Wob + (size_t)(n0 + r0) * E_E + (kt) * 64 + scol,                \
              bd + r0 * 64 + sc * 8);                                          \
      gload16(Wob + (size_t)(n0 + r0 + 32) * E_E + (kt) * 64 + scol,           \
              bd + (r0 + 32) * 64 + sc * 8);                                   \
      gload16(Wob + (size_t)(n0 + r0 + 64) * E_E + (kt) * 64 + scol,           \
              bd + (r0 + 64) * 64 + sc * 8);                                   \
      gload16(Wob + (size_t)(n0 + r0 + 96) * E_E + (kt) * 64 + scol,           \
              bd + (r0 + 96) * 64 + sc * 8);                                   \
    } while (0)

  f32x4 acc[2][4];
  #pragma unroll
  for (int mi = 0; mi < 2; ++mi)
    #pragma unroll
    for (int ni = 0; ni < 4; ++ni) {
      const float bb = bo[n0 + wc * 64 + ni * 16 + lr];
      acc[mi][ni] = f32x4{bb, bb, bb, bb};
    }

  OSTAGE(0, 0);
  __syncthreads();
  int cur = 0;

  for (int kt = 0; kt < 16; ++kt) {
    if (kt < 15) OSTAGE(cur ^ 1, kt + 1);

    const char* Ac = (const char*)&As[cur][0][0];
    const char* Bc = (const char*)&Bs[cur][0][0];
    bf16x8 af[2][2], bfr[4][2];
    #pragma unroll
    for (int mi = 0; mi < 2; ++mi) {
      const int row = wr * 32 + mi * 16 + lr;
      #pragma unroll
      for (int kb = 0; kb < 2; ++kb)
        af[mi][kb] = *(const bf16x8*)(Ac + row * 128 + (((kb * 4 + lg) ^ (row & 7)) << 4));
    }
    #pragma unroll
    for (int ni = 0; ni < 4; ++ni) {
      const int row = wc * 64 + ni * 16 + lr;
      #pragma unroll
      for (int kb = 0; kb < 2; ++kb)
        bfr[ni][kb] = *(const bf16x8*)(Bc + row * 128 + (((kb * 4 + lg) ^ (row & 7)) << 4));
    }
    __builtin_amdgcn_s_setprio(1);
    #pragma unroll
    for (int kb = 0; kb < 2; ++kb)
      #pragma unroll
      for (int mi = 0; mi < 2; ++mi)
        #pragma unroll
        for (int ni = 0; ni < 4; ++ni)
          acc[mi][ni] = mfma16(af[mi][kb], bfr[ni][kb], acc[mi][ni]);
    __builtin_amdgcn_s_setprio(0);

    __syncthreads();
    cur ^= 1;
  }
  #undef OSTAGE

  #pragma unroll
  for (int mi = 0; mi < 2; ++mi)
    #pragma unroll
    for (int ni = 0; ni < 4; ++ni) {
      const int nn = n0 + wc * 64 + ni * 16 + lr;
      #pragma unroll
      for (int r = 0; r < 4; ++r) {
        const int mm = m0 + wr * 32 + mi * 16 + lg * 4 + r;
        out[(size_t)mm * E_E + nn] = acc[mi][ni][r];
      }
    }
}

extern "C" void kernel_launch(void* const* d_in, const int* in_sizes, int n_in,
                              void* d_out, int out_size, void* d_ws, size_t ws_size,
                              hipStream_t stream) {
  const float* EPq = (const float*)d_in[0];
  const float* EPk = (const float*)d_in[1];
  const float* EPv = (const float*)d_in[2];
  const float* Wq  = (const float*)d_in[3];
  const float* bq  = (const float*)d_in[4];
  const float* Wk  = (const float*)d_in[5];
  const float* bk  = (const float*)d_in[6];
  const float* Wv  = (const float*)d_in[7];
  const float* bv  = (const float*)d_in[8];
  const float* Wo  = (const float*)d_in[9];
  const float* bo  = (const float*)d_in[10];
  float* out = (float*)d_out;

  unsigned short* ws = (unsigned short*)d_ws;
  const size_t SZ = (size_t)N_B * H_H * L_L * D_H;  // 4,194,304
  unsigned short* Qb  = ws;
  unsigned short* Kb  = Qb + SZ;
  unsigned short* Vtb = Kb + SZ;
  unsigned short* Ab  = Vtb + SZ;
  unsigned short* Wob = Ab + SZ;

  qkv_gemm_kernel<<<1024, 256, 0, stream>>>(
      EPq, EPk, EPv, Wq, Wk, Wv, bq, bk, bv, Wo, Wob, Qb, Kb, Vtb);
  attn_mfma_kernel<<<512, 256, 0, stream>>>(Qb, Kb, Vtb, Ab);
  out_gemm_kernel<<<512, 256, 0, stream>>>(Ab, Wob, bo, out);
}

// Round 18
// 71.248 us; speedup vs baseline: 1.0250x; 1.0250x over previous
//
#include <hip/hip_runtime.h>

#define N_B 2
#define L_L 2048
#define E_E 1024
#define H_H 16
#define D_H 64
#define LDSP 72  // padded LDS row stride (ushorts) for qkv kernel

typedef __bf16 bf16x8 __attribute__((ext_vector_type(8)));
typedef float f32x4 __attribute__((ext_vector_type(4)));
typedef short s16x8 __attribute__((ext_vector_type(8)));
typedef unsigned short u16x4 __attribute__((ext_vector_type(4)));

__device__ __forceinline__ f32x4 mfma16(bf16x8 a, bf16x8 b, f32x4 c) {
  return __builtin_amdgcn_mfma_f32_16x16x32_bf16(a, b, c, 0, 0, 0);
}

__device__ __forceinline__ unsigned short f2bf(float x) {
  unsigned int u = __float_as_uint(x);
  u = (u + 0x7fffu + ((u >> 16) & 1u)) >> 16;
  return (unsigned short)u;
}

__device__ __forceinline__ unsigned int cvtpk(float lo, float hi) {
  unsigned int r;
  asm("v_cvt_pk_bf16_f32 %0, %1, %2" : "=v"(r) : "v"(lo), "v"(hi));
  return r;
}

__device__ __forceinline__ void swap32(unsigned int& a, unsigned int& b) {
  asm("v_permlane32_swap_b32 %0, %1" : "+v"(a), "+v"(b));
}
__device__ __forceinline__ void swap16(unsigned int& a, unsigned int& b) {
  asm("v_permlane16_swap_b32 %0, %1" : "+v"(a), "+v"(b));
}

__device__ __forceinline__ float exp2a(float x) {  // 2^x, single v_exp_f32
  float r;
  asm("v_exp_f32 %0, %1" : "=v"(r) : "v"(x));
  return r;
}

// async global->LDS 16B DMA (dest linear per wave)
__device__ __forceinline__ void gload16(const void* g, void* l) {
  __builtin_amdgcn_global_load_lds(
      (__attribute__((address_space(1))) void*)g,
      (__attribute__((address_space(3))) void*)l, 16, 0, 0);
}

// Build PV A-fragment from swapped-QK^T C-layout values (in-register, T12).
__device__ __forceinline__ bf16x8 pack_frag(const f32x4& plo, const f32x4& phi) {
  unsigned int x0 = cvtpk(plo[0], plo[1]), x1 = cvtpk(plo[2], plo[3]);
  unsigned int x2 = cvtpk(phi[0], phi[1]), x3 = cvtpk(phi[2], phi[3]);
  swap32(x0, x2); swap16(x0, x2);
  swap32(x1, x3); swap16(x1, x3);
  union { unsigned int u[4]; bf16x8 v; } f;
  f.u[0] = x0; f.u[1] = x1; f.u[2] = x2; f.u[3] = x3;
  return f.v;
}

// K1: QKV projection as MFMA GEMM (round-8 structure).
__global__ __launch_bounds__(256) void qkv_gemm_kernel(
    const float* __restrict__ EPq, const float* __restrict__ EPk, const float* __restrict__ EPv,
    const float* __restrict__ Wq, const float* __restrict__ Wk, const float* __restrict__ Wv,
    const float* __restrict__ bq, const float* __restrict__ bk, const float* __restrict__ bv,
    const float* __restrict__ Wo, unsigned short* __restrict__ Wob,
    unsigned short* __restrict__ Qb, unsigned short* __restrict__ Kb,
    unsigned short* __restrict__ Vtb) {
  __shared__ __attribute__((aligned(16))) unsigned short Xs[64][LDSP];
  __shared__ __attribute__((aligned(16))) unsigned short Ws[64][LDSP];
  const int tid = threadIdx.x;
  const int wid = tid >> 6;
  const int lane = tid & 63;
  const int lr = lane & 15;
  const int lg = lane >> 4;
  const int nh = blockIdx.x >> 5;
  const int l0 = (blockIdx.x & 31) * 64;
  const int n = nh >> 4;
  const int h = nh & 15;
  const float SCQ = 0.03125f * 1.44269504089f;

  {
    const int i = blockIdx.x * 256 + tid;
    const float4 f = ((const float4*)Wo)[i];
    u16x4 v = { f2bf(f.x), f2bf(f.y), f2bf(f.z), f2bf(f.w) };
    *(u16x4*)&Wob[(size_t)i * 4] = v;
  }

  #pragma unroll
  for (int mat = 0; mat < 3; ++mat) {
    const float* X = (mat == 0) ? EPq : (mat == 1) ? EPk : EPv;
    const float* W = (mat == 0) ? Wq : (mat == 1) ? Wk : Wv;
    const float* bias = (mat == 0) ? bq : (mat == 1) ? bk : bv;
    const float osc = (mat == 0) ? SCQ : 1.0f;

    const float* xb = X + ((size_t)(n * L_L + l0)) * E_E + h * D_H;
    #pragma unroll
    for (int it = 0; it < 4; ++it) {
      const int idx = it * 256 + tid;
      const int row = idx >> 4, c = idx & 15;
      const float4 f = *(const float4*)(xb + (size_t)row * E_E + c * 4);
      u16x4 v = { f2bf(f.x), f2bf(f.y), f2bf(f.z), f2bf(f.w) };
      *(u16x4*)&Xs[row][c * 4] = v;
    }
    #pragma unroll
    for (int it = 0; it < 4; ++it) {
      const int idx = it * 256 + tid;
      const int row = idx >> 4, c = idx & 15;
      const float4 f = *(const float4*)(W + idx * 4);
      u16x4 v = { f2bf(f.x), f2bf(f.y), f2bf(f.z), f2bf(f.w) };
      *(u16x4*)&Ws[row][c * 4] = v;
    }
    __syncthreads();

    const bf16x8 a0 = *(const bf16x8*)&Xs[wid * 16 + lr][lg * 8];
    const bf16x8 a1 = *(const bf16x8*)&Xs[wid * 16 + lr][32 + lg * 8];
    f32x4 acc[4];
    #pragma unroll
    for (int t = 0; t < 4; ++t) {
      const float bb = bias[t * 16 + lr];
      acc[t] = f32x4{bb, bb, bb, bb};
      const bf16x8 b0 = *(const bf16x8*)&Ws[t * 16 + lr][lg * 8];
      const bf16x8 b1 = *(const bf16x8*)&Ws[t * 16 + lr][32 + lg * 8];
      acc[t] = mfma16(a0, b0, acc[t]);
      acc[t] = mfma16(a1, b1, acc[t]);
    }
    __syncthreads();

    #pragma unroll
    for (int t = 0; t < 4; ++t)
      #pragma unroll
      for (int r = 0; r < 4; ++r)
        Xs[wid * 16 + lg * 4 + r][t * 16 + lr] = f2bf(acc[t][r] * osc);
    __syncthreads();

    if (mat < 2) {
      unsigned short* dst = ((mat == 0) ? Qb : Kb) + ((size_t)nh * L_L + l0) * D_H;
      #pragma unroll
      for (int it = 0; it < 2; ++it) {
        const int idx = it * 256 + tid;
        const int row = idx >> 3, c = idx & 7;
        *(s16x8*)(dst + (size_t)row * D_H + c * 8) = *(s16x8*)&Xs[row][c * 8];
      }
    } else {
      #pragma unroll
      for (int it = 0; it < 2; ++it) {
        const int idx = it * 256 + tid;
        const int d = idx & 63, c = idx >> 6;
        s16x8 v;
        #pragma unroll
        for (int j = 0; j < 8; ++j) v[j] = (short)Xs[c * 8 + j][d];
        *(s16x8*)(Vtb + ((size_t)nh * D_H + d) * L_L + l0 + c * 8) = v;
      }
    }
    __syncthreads();
  }
}

// K2: flash attention (round-13 exact: 32 q/wave, static-m softmax,
// QKT(t+1) || SMPV(t) pipeline with QKT issued BEFORE the DMA stage,
// 2K+2V buffers 32KB, 1 barrier/iter).
__global__ __launch_bounds__(256, 2) void attn_mfma_kernel(
    const unsigned short* __restrict__ Qb, const unsigned short* __restrict__ Kb,
    const unsigned short* __restrict__ Vtb, unsigned short* __restrict__ Ab) {
  __shared__ __attribute__((aligned(16))) unsigned short KS[2][64][64]; // 16 KB
  __shared__ __attribute__((aligned(16))) unsigned short VS[2][64][64]; // 16 KB

  const int tid = threadIdx.x;
  const int wid = tid >> 6;       // 0..3
  const int lane = tid & 63;
  const int lr = lane & 15;
  const int lg = lane >> 4;

  const int bid = ((blockIdx.x & 7) << 6) + (blockIdx.x >> 3);
  const int nh = bid >> 4;
  const int q0w = ((bid & 15) << 7) + wid * 32;   // 32 q-rows per wave

  const unsigned short* gQ = Qb + ((size_t)nh * L_L + q0w) * D_H;
  const unsigned short* gK = Kb + (size_t)nh * L_L * D_H;
  const unsigned short* gV = Vtb + (size_t)nh * D_H * L_L;

  bf16x8 bQ[2][2];
  #pragma unroll
  for (int qb = 0; qb < 2; ++qb)
    #pragma unroll
    for (int c2 = 0; c2 < 2; ++c2)
      bQ[qb][c2] = *(const bf16x8*)(gQ + (qb * 16 + lr) * D_H + c2 * 32 + lg * 8);

  const s16x8 ones16 = {0x3F80,0x3F80,0x3F80,0x3F80,0x3F80,0x3F80,0x3F80,0x3F80};
  const bf16x8 ones = *(const bf16x8*)&ones16;

  const int srow0 = tid >> 3, sch0 = tid & 7;
  const int srow1 = srow0 + 32;
  const int kc0 = (sch0 ^ (srow0 & 7)) * 8;
  const int kc1 = (sch0 ^ (srow1 & 7)) * 8;

  #define STAGE_K(buf, ktt)                                                    \
    do {                                                                       \
      unsigned short* kd = &KS[buf][0][0];                                     \
      gload16(gK + (size_t)((ktt) * 64 + srow0) * D_H + kc0,                   \
              kd + srow0 * 64 + sch0 * 8);                                     \
      gload16(gK + (size_t)((ktt) * 64 + srow1) * D_H + kc1,                   \
              kd + srow1 * 64 + sch0 * 8);                                     \
    } while (0)
  #define STAGE_V(buf, ktt)                                                    \
    do {                                                                       \
      unsigned short* vd = &VS[buf][0][0];                                     \
      gload16(gV + (size_t)srow0 * L_L + (ktt) * 64 + kc0,                     \
              vd + srow0 * 64 + sch0 * 8);                                     \
      gload16(gV + (size_t)srow1 * L_L + (ktt) * 64 + kc1,                     \
              vd + srow1 * 64 + sch0 * 8);                                     \
    } while (0)

  f32x4 acc0[4] = {f32x4{0,0,0,0},f32x4{0,0,0,0},f32x4{0,0,0,0},f32x4{0,0,0,0}};
  f32x4 acc1[4] = {f32x4{0,0,0,0},f32x4{0,0,0,0},f32x4{0,0,0,0},f32x4{0,0,0,0}};
  f32x4 lacc0 = {0,0,0,0}, lacc1 = {0,0,0,0};
  f32x4 svA0[4], svA1[4], svB0[4], svB1[4];

  #define QKT(SQ0, SQ1, kbuf)                                                  \
    do {                                                                       \
      const char* Kc = (const char*)&KS[kbuf][0][0];                           \
      __builtin_amdgcn_s_setprio(1);                                           \
      _Pragma("unroll")                                                        \
      for (int kb = 0; kb < 4; ++kb) {                                         \
        const int row = kb * 16 + lr;                                          \
        const bf16x8 a0 = *(const bf16x8*)(Kc + row * 128 + ((lg ^ (row & 7)) << 4)); \
        const bf16x8 a1 = *(const bf16x8*)(Kc + row * 128 + (((4 + lg) ^ (row & 7)) << 4)); \
        SQ0[kb] = mfma16(a1, bQ[0][1], mfma16(a0, bQ[0][0], f32x4{0,0,0,0}));  \
        SQ1[kb] = mfma16(a1, bQ[1][1], mfma16(a0, bQ[1][0], f32x4{0,0,0,0}));  \
      }                                                                        \
      __builtin_amdgcn_s_setprio(0);                                           \
    } while (0)

  #define SMPV(SQ0, SQ1, vbuf)                                                 \
    do {                                                                       \
      _Pragma("unroll")                                                        \
      for (int kb = 0; kb < 4; ++kb)                                           \
        _Pragma("unroll")                                                      \
        for (int r = 0; r < 4; ++r) {                                          \
          SQ0[kb][r] = exp2a(SQ0[kb][r]);                                      \
          SQ1[kb][r] = exp2a(SQ1[kb][r]);                                      \
        }                                                                      \
      bf16x8 aP0[2], aP1[2];                                                   \
      aP0[0] = pack_frag(SQ0[0], SQ0[1]); aP0[1] = pack_frag(SQ0[2], SQ0[3]);  \
      aP1[0] = pack_frag(SQ1[0], SQ1[1]); aP1[1] = pack_frag(SQ1[2], SQ1[3]);  \
      const char* Vc = (const char*)&VS[vbuf][0][0];                           \
      __builtin_amdgcn_s_setprio(1);                                           \
      lacc0 = mfma16(aP0[0], ones, lacc0); lacc0 = mfma16(aP0[1], ones, lacc0);\
      lacc1 = mfma16(aP1[0], ones, lacc1); lacc1 = mfma16(aP1[1], ones, lacc1);\
      _Pragma("unroll")                                                        \
      for (int t = 0; t < 4; ++t) {                                            \
        const int row = t * 16 + lr;                                           \
        const bf16x8 v0 = *(const bf16x8*)(Vc + row * 128 + ((lg ^ (row & 7)) << 4)); \
        const bf16x8 v1 = *(const bf16x8*)(Vc + row * 128 + (((4 + lg) ^ (row & 7)) << 4)); \
        acc0[t] = mfma16(aP0[0], v0, acc0[t]); acc0[t] = mfma16(aP0[1], v1, acc0[t]); \
        acc1[t] = mfma16(aP1[0], v0, acc1[t]); acc1[t] = mfma16(aP1[1], v1, acc1[t]); \
      }                                                                        \
      __builtin_amdgcn_s_setprio(0);                                           \
    } while (0)

  STAGE_K(0, 0);
  STAGE_K(1, 1);
  STAGE_V(0, 0);
  __syncthreads();
  QKT(svA0, svA1, 0);
  __syncthreads();

  #pragma unroll 1
  for (int t2 = 0; t2 < 16; ++t2) {
    {
      const int t = 2 * t2;
      QKT(svB0, svB1, 1);
      if (t2 < 15) STAGE_K(0, t + 2);
      STAGE_V(1, t + 1);
      SMPV(svA0, svA1, 0);
      __syncthreads();
    }
    {
      const int t = 2 * t2 + 1;
      if (t2 < 15) {
        QKT(svA0, svA1, 0);
        STAGE_K(1, t + 2);
        STAGE_V(0, t + 1);
      }
      SMPV(svB0, svB1, 1);
      __syncthreads();
    }
  }
  #undef STAGE_K
  #undef STAGE_V
  #undef QKT
  #undef SMPV

  const int n = nh >> 4, h = nh & 15;
  #pragma unroll
  for (int qb = 0; qb < 2; ++qb) {
    const f32x4& la = qb ? lacc1 : lacc0;
    f32x4* ac = qb ? acc1 : acc0;
    f32x4 inv;
    #pragma unroll
    for (int r = 0; r < 4; ++r) inv[r] = 1.0f / la[r];
    const int qbase = q0w + qb * 16 + 4 * lg;
    #pragma unroll
    for (int t = 0; t < 4; ++t)
      #pragma unroll
      for (int r = 0; r < 4; ++r)
        Ab[((size_t)(n * L_L + qbase + r)) * E_E + h * D_H + t * 16 + lr] =
            f2bf(ac[t][r] * inv[r]);
  }
}

// K3: out = A(bf16) @ Wo^T(bf16) + bo, fp32 out (round-8 structure:
// BM=64 x BN=128, grid 512, global_load_lds dbuf, 1 barrier/iter).
__global__ __launch_bounds__(256, 2) void out_gemm_kernel(
    const unsigned short* __restrict__ Ab, const unsigned short* __restrict__ Wob,
    const float* __restrict__ bo, float* __restrict__ out) {
  __shared__ __attribute__((aligned(16))) unsigned short As[2][64][64];   // 16KB
  __shared__ __attribute__((aligned(16))) unsigned short Bs[2][128][64];  // 32KB
  const int tid = threadIdx.x;
  const int wid = tid >> 6;
  const int lane = tid & 63;
  const int lr = lane & 15;
  const int lg = lane >> 4;

  const int bid = ((blockIdx.x & 7) << 6) + (blockIdx.x >> 3);
  const int m0 = (bid >> 3) * 64;
  const int n0 = (bid & 7) * 128;
  const int wr = wid >> 1, wc = wid & 1;

  const int r0 = tid >> 3, sc = tid & 7;
  const int scol = (sc ^ (r0 & 7)) * 8;

  #define OSTAGE(buf, kt)                                                      \
    do {                                                                       \
      unsigned short* ad = &As[buf][0][0];                                     \
      unsigned short* bd = &Bs[buf][0][0];                                     \
      gload16(Ab + (size_t)(m0 + r0) * E_E + (kt) * 64 + scol,                 \
              ad + r0 * 64 + sc * 8);                                          \
      gload16(Ab + (size_t)(m0 + r0 + 32) * E_E + (kt) * 64 + scol,            \
              ad + (r0 + 32) * 64 + sc * 8);                                   \
      gload16(Wob + (size_t)(n0 + r0) * E_E + (kt) * 64 + scol,                \
              bd + r0 * 64 + sc * 8);                                          \
      gload16(Wob + (size_t)(n0 + r0 + 32) * E_E + (kt) * 64 + scol,           \
              bd + (r0 + 32) * 64 + sc * 8);                                   \
      gload16(Wob + (size_t)(n0 + r0 + 64) * E_E + (kt) * 64 + scol,           \
              bd + (r0 + 64) * 64 + sc * 8);                                   \
      gload16(Wob + (size_t)(n0 + r0 + 96) * E_E + (kt) * 64 + scol,           \
              bd + (r0 + 96) * 64 + sc * 8);                                   \
    } while (0)

  f32x4 acc[2][4];
  #pragma unroll
  for (int mi = 0; mi < 2; ++mi)
    #pragma unroll
    for (int ni = 0; ni < 4; ++ni) {
      const float bb = bo[n0 + wc * 64 + ni * 16 + lr];
      acc[mi][ni] = f32x4{bb, bb, bb, bb};
    }

  OSTAGE(0, 0);
  __syncthreads();
  int cur = 0;

  for (int kt = 0; kt < 16; ++kt) {
    if (kt < 15) OSTAGE(cur ^ 1, kt + 1);

    const char* Ac = (const char*)&As[cur][0][0];
    const char* Bc = (const char*)&Bs[cur][0][0];
    bf16x8 af[2][2], bfr[4][2];
    #pragma unroll
    for (int mi = 0; mi < 2; ++mi) {
      const int row = wr * 32 + mi * 16 + lr;
      #pragma unroll
      for (int kb = 0; kb < 2; ++kb)
        af[mi][kb] = *(const bf16x8*)(Ac + row * 128 + (((kb * 4 + lg) ^ (row & 7)) << 4));
    }
    #pragma unroll
    for (int ni = 0; ni < 4; ++ni) {
      const int row = wc * 64 + ni * 16 + lr;
      #pragma unroll
      for (int kb = 0; kb < 2; ++kb)
        bfr[ni][kb] = *(const bf16x8*)(Bc + row * 128 + (((kb * 4 + lg) ^ (row & 7)) << 4));
    }
    __builtin_amdgcn_s_setprio(1);
    #pragma unroll
    for (int kb = 0; kb < 2; ++kb)
      #pragma unroll
      for (int mi = 0; mi < 2; ++mi)
        #pragma unroll
        for (int ni = 0; ni < 4; ++ni)
          acc[mi][ni] = mfma16(af[mi][kb], bfr[ni][kb], acc[mi][ni]);
    __builtin_amdgcn_s_setprio(0);

    __syncthreads();
    cur ^= 1;
  }
  #undef OSTAGE

  #pragma unroll
  for (int mi = 0; mi < 2; ++mi)
    #pragma unroll
    for (int ni = 0; ni < 4; ++ni) {
      const int nn = n0 + wc * 64 + ni * 16 + lr;
      #pragma unroll
      for (int r = 0; r < 4; ++r) {
        const int mm = m0 + wr * 32 + mi * 16 + lg * 4 + r;
        out[(size_t)mm * E_E + nn] = acc[mi][ni][r];
      }
    }
}

extern "C" void kernel_launch(void* const* d_in, const int* in_sizes, int n_in,
                              void* d_out, int out_size, void* d_ws, size_t ws_size,
                              hipStream_t stream) {
  const float* EPq = (const float*)d_in[0];
  const float* EPk = (const float*)d_in[1];
  const float* EPv = (const float*)d_in[2];
  const float* Wq  = (const float*)d_in[3];
  const float* bq  = (const float*)d_in[4];
  const float* Wk  = (const float*)d_in[5];
  const float* bk  = (const float*)d_in[6];
  const float* Wv  = (const float*)d_in[7];
  const float* bv  = (const float*)d_in[8];
  const float* Wo  = (const float*)d_in[9];
  const float* bo  = (const float*)d_in[10];
  float* out = (float*)d_out;

  unsigned short* ws = (unsigned short*)d_ws;
  const size_t SZ = (size_t)N_B * H_H * L_L * D_H;  // 4,194,304
  unsigned short* Qb  = ws;
  unsigned short* Kb  = Qb + SZ;
  unsigned short* Vtb = Kb + SZ;
  unsigned short* Ab  = Vtb + SZ;
  unsigned short* Wob = Ab + SZ;

  qkv_gemm_kernel<<<1024, 256, 0, stream>>>(
      EPq, EPk, EPv, Wq, Wk, Wv, bq, bk, bv, Wo, Wob, Qb, Kb, Vtb);
  attn_mfma_kernel<<<512, 256, 0, stream>>>(Qb, Kb, Vtb, Ab);
  out_gemm_kernel<<<512, 256, 0, stream>>>(Ab, Wob, bo, out);
}